// Round 8
// baseline (449.732 us; speedup 1.0000x reference)
//
#include <hip/hip_runtime.h>

#define SS 512
#define DD 768
#define TT 64

typedef __attribute__((ext_vector_type(2))) float f32x2;

__device__ __forceinline__ f32x2 vmax2(f32x2 a, f32x2 b) {
    return __builtin_elementwise_max(a, b);
}

// ---------------------------------------------------------------------------
// Kernel 1: emissions GEMM  em[b*512+s][t] = sum_d x[b,s,d]*W[t,d] + bias[t]
// 64x64 tile, grid 512 (2 blocks/CU), 256 threads, thread tile 4x4.
// ---------------------------------------------------------------------------
__global__ __launch_bounds__(256) void emis_gemm(
    const float* __restrict__ X, const float* __restrict__ W,
    const float* __restrict__ bias, float* __restrict__ em)
{
    __shared__ __align__(16) float Xs[16][68];
    __shared__ __align__(16) float Ws[16][68];

    const int tid = threadIdx.x;
    const int m0  = blockIdx.x * 64;
    const int tm  = tid >> 4;
    const int tn  = tid & 15;
    const int lr  = tid >> 2;
    const int lk  = tid & 3;

    float acc[4][4];
#pragma unroll
    for (int i = 0; i < 4; i++)
#pragma unroll
        for (int j = 0; j < 4; j++) acc[i][j] = 0.f;

    float4 xr, wr;
    xr = *(const float4*)&X[(size_t)(m0 + lr) * DD + lk * 4];
    wr = *(const float4*)&W[(size_t)lr * DD + lk * 4];

    for (int t = 0; t < 48; t++) {
        Xs[lk * 4 + 0][lr] = xr.x;  Xs[lk * 4 + 1][lr] = xr.y;
        Xs[lk * 4 + 2][lr] = xr.z;  Xs[lk * 4 + 3][lr] = xr.w;
        Ws[lk * 4 + 0][lr] = wr.x;  Ws[lk * 4 + 1][lr] = wr.y;
        Ws[lk * 4 + 2][lr] = wr.z;  Ws[lk * 4 + 3][lr] = wr.w;
        __syncthreads();

        if (t < 47) {
            const int k0 = (t + 1) * 16;
            xr = *(const float4*)&X[(size_t)(m0 + lr) * DD + k0 + lk * 4];
            wr = *(const float4*)&W[(size_t)lr * DD + k0 + lk * 4];
        }

#pragma unroll
        for (int k = 0; k < 16; k++) {
            float a[4], bv[4];
            *(float4*)&a[0]  = *(const float4*)&Xs[k][tm * 4];
            *(float4*)&bv[0] = *(const float4*)&Ws[k][tn * 4];
#pragma unroll
            for (int i = 0; i < 4; i++)
#pragma unroll
                for (int j = 0; j < 4; j++)
                    acc[i][j] = fmaf(a[i], bv[j], acc[i][j]);
        }
        __syncthreads();
    }

    const float4 bv4 = *(const float4*)&bias[tn * 4];
#pragma unroll
    for (int i = 0; i < 4; i++) {
        const size_t row = (size_t)(m0 + tm * 4 + i);
        float4 o;
        o.x = acc[i][0] + bv4.x;  o.y = acc[i][1] + bv4.y;
        o.z = acc[i][2] + bv4.z;  o.w = acc[i][3] + bv4.w;
        *(float4*)&em[row * TT + tn * 4] = o;
    }
}

// ---------------------------------------------------------------------------
// Kernel 2: Viterbi forward, VALUE ONLY, XOR-indexed butterfly reduce-scatter.
// One wave per batch (64 x 64). Lane p owns score[p] and trans ROW p.
// Slot j (f32x2) holds candidate values for indices (p^j, p^(j+32)):
//   pk[j] = (score_p + trans[p][p^j], score_p + trans[p][p^(j+32)])
// Butterfly stage mask m: pk[j] = max(pk[j], shfl_xor(pk[j^m], m)) for
// surviving slots (j & (2m-1)) == 0 -- ALL STATIC register indices, no LDS
// in the step loop. After masks 1..16 slot0 covers (p, p^32) reduced over
// 32 lanes; final: ns = max(pk0.x, shfl_xor(pk0.y,32)) + em. Value-exact:
// candidates rounded once as (score+trans) like the reference; max is
// exact; +em (lane-constant) commutes with max (monotone rounding).
// ---------------------------------------------------------------------------
__global__ __launch_bounds__(64, 1) void viterbi_fwd(
    const float* __restrict__ em, const float* __restrict__ trans,
    float* __restrict__ scoreHist, int* __restrict__ bestTag)
{
    __shared__ __align__(16) float tr_lds[4096];

    const int b    = blockIdx.x;
    const int lane = threadIdx.x;
    const float* emb = em + (size_t)b * SS * TT;
    float* sh = scoreHist + (size_t)b * SS * TT;

    // stage trans into LDS coalesced, then read the lane's permuted row
    {
        float4* dst = (float4*)tr_lds;
        const float4* src = (const float4*)trans;
#pragma unroll
        for (int i = 0; i < 16; i++) dst[lane + i * 64] = src[lane + i * 64];
    }
    __syncthreads();

    // tpk[j] = (trans[p][p^j], trans[p][p^(j+32)])
    f32x2 tpk[32];
#pragma unroll
    for (int j = 0; j < 32; j++) {
        const int c = lane ^ j;
        tpk[j].x = tr_lds[lane * TT + c];
        tpk[j].y = tr_lds[lane * TT + (c ^ 32)];
    }

    float sc = emb[lane];   // score_0[lane]
    sh[lane] = sc;

    float er0 = emb[1 * TT + lane];
    float er1 = emb[2 * TT + lane];
    float er2 = emb[3 * TT + lane];
    float er3 = emb[4 * TT + lane];

    auto step = [&](int s, float em_v) {
        f32x2 sc2; sc2.x = sc; sc2.y = sc;
        f32x2 pk[32];
#pragma unroll
        for (int j = 0; j < 32; j++) pk[j] = tpk[j] + sc2;   // v_pk_add_f32

        // stage m=1: slots j even
#pragma unroll
        for (int j = 0; j < 32; j += 2) {
            f32x2 o;
            o.x = __shfl_xor(pk[j + 1].x, 1, 64);
            o.y = __shfl_xor(pk[j + 1].y, 1, 64);
            pk[j] = vmax2(pk[j], o);
        }
        // stage m=2: j % 4 == 0
#pragma unroll
        for (int j = 0; j < 32; j += 4) {
            f32x2 o;
            o.x = __shfl_xor(pk[j + 2].x, 2, 64);
            o.y = __shfl_xor(pk[j + 2].y, 2, 64);
            pk[j] = vmax2(pk[j], o);
        }
        // stage m=4
#pragma unroll
        for (int j = 0; j < 32; j += 8) {
            f32x2 o;
            o.x = __shfl_xor(pk[j + 4].x, 4, 64);
            o.y = __shfl_xor(pk[j + 4].y, 4, 64);
            pk[j] = vmax2(pk[j], o);
        }
        // stage m=8
#pragma unroll
        for (int j = 0; j < 32; j += 16) {
            f32x2 o;
            o.x = __shfl_xor(pk[j + 8].x, 8, 64);
            o.y = __shfl_xor(pk[j + 8].y, 8, 64);
            pk[j] = vmax2(pk[j], o);
        }
        // stage m=16
        {
            f32x2 o;
            o.x = __shfl_xor(pk[16].x, 16, 64);
            o.y = __shfl_xor(pk[16].y, 16, 64);
            pk[0] = vmax2(pk[0], o);
        }
        // final m=32: slot0 = (index p, index p^32)
        const float hi = __shfl_xor(pk[0].y, 32, 64);
        sc = fmaxf(pk[0].x, hi) + em_v;

        sh[s * TT + lane] = sc;   // history for bp_kernel
    };

    for (int sb = 1; sb <= 505; sb += 4) {
        // keep-alive: discourage rematerialization of tpk
#pragma unroll
        for (int j = 0; j < 32; j++) asm volatile("" : "+v"(tpk[j]));

        step(sb + 0, er0);  er0 = emb[(sb + 4) * TT + lane];
        step(sb + 1, er1);  er1 = emb[(sb + 5) * TT + lane];
        step(sb + 2, er2);  er2 = emb[(sb + 6) * TT + lane];
        step(sb + 3, er3);  er3 = emb[((sb + 7) <= 511 ? (sb + 7) : 511) * TT + lane];
    }
    step(509, er0);
    step(510, er1);
    step(511, er2);

    // final argmax across lanes (first-index ties)
    float fv = sc;
    int   fa = lane;
#pragma unroll
    for (int m = 1; m <= 32; m <<= 1) {
        const float vo = __shfl_xor(fv, m, 64);
        const int   ao = __shfl_xor(fa, m, 64);
        if (vo > fv || (vo == fv && ao < fa)) { fv = vo; fa = ao; }
    }
    if (lane == 0) bestTag[b] = fa;
}

// ---------------------------------------------------------------------------
// Kernel 3: backpointer recompute, massively parallel. One wave per (b,s),
// lane = cur. v[p] = (score_{s-1}[p] + trans[p][cur]) + em_s[cur] with
// exact reference rounding; left-wins tournament == first-index argmax.
// ---------------------------------------------------------------------------
__global__ __launch_bounds__(256) void bp_kernel(
    const float* __restrict__ scoreHist, const float* __restrict__ em,
    const float* __restrict__ trans, unsigned char* __restrict__ hist8)
{
    __shared__ __align__(16) float tr_lds[4096];  // 16 KB: trans[64][64]
    const int tid = threadIdx.x;
    {
        const float4* src = (const float4*)trans;
        float4* dst = (float4*)tr_lds;
        for (int i = tid; i < 1024; i += 256) dst[i] = src[i];
    }
    __syncthreads();

    const int wv   = tid >> 6;
    const int lane = tid & 63;
    const int g    = blockIdx.x * 4 + wv;   // 0..32703
    const int b    = g / 511;
    const int s    = 1 + (g % 511);

    const float4* sb4 = (const float4*)(scoreHist + ((size_t)b * SS + (s - 1)) * TT);
    const float em_v = em[((size_t)b * SS + s) * TT + lane];

    float treg[TT];
#pragma unroll
    for (int p = 0; p < TT; p++) treg[p] = tr_lds[p * TT + lane];

    float4 sq[16];
#pragma unroll
    for (int i = 0; i < 16; i++) sq[i] = sb4[i];

    float v[TT];
#pragma unroll
    for (int i = 0; i < 16; i++) {
        v[4 * i + 0] = (sq[i].x + treg[4 * i + 0]) + em_v;
        v[4 * i + 1] = (sq[i].y + treg[4 * i + 1]) + em_v;
        v[4 * i + 2] = (sq[i].z + treg[4 * i + 2]) + em_v;
        v[4 * i + 3] = (sq[i].w + treg[4 * i + 3]) + em_v;
    }
    // left-wins tournament (== numpy first-index argmax)
    float m1[32]; int a1[32];
#pragma unroll
    for (int i = 0; i < 32; i++) {
        const bool t = v[2 * i + 1] > v[2 * i];
        m1[i] = t ? v[2 * i + 1] : v[2 * i];
        a1[i] = 2 * i + (t ? 1 : 0);
    }
    float m2[16]; int a2[16];
#pragma unroll
    for (int i = 0; i < 16; i++) {
        const bool t = m1[2 * i + 1] > m1[2 * i];
        m2[i] = t ? m1[2 * i + 1] : m1[2 * i];
        a2[i] = t ? a1[2 * i + 1] : a1[2 * i];
    }
    float m3[8]; int a3[8];
#pragma unroll
    for (int i = 0; i < 8; i++) {
        const bool t = m2[2 * i + 1] > m2[2 * i];
        m3[i] = t ? m2[2 * i + 1] : m2[2 * i];
        a3[i] = t ? a2[2 * i + 1] : a2[2 * i];
    }
    float m4[4]; int a4[4];
#pragma unroll
    for (int i = 0; i < 4; i++) {
        const bool t = m3[2 * i + 1] > m3[2 * i];
        m4[i] = t ? m3[2 * i + 1] : m3[2 * i];
        a4[i] = t ? a3[2 * i + 1] : a3[2 * i];
    }
    float m5[2]; int a5[2];
#pragma unroll
    for (int i = 0; i < 2; i++) {
        const bool t = m4[2 * i + 1] > m4[2 * i];
        m5[i] = t ? m4[2 * i + 1] : m4[2 * i];
        a5[i] = t ? a4[2 * i + 1] : a4[2 * i];
    }
    const bool t6 = m5[1] > m5[0];
    const int barg = t6 ? a5[1] : a5[0];

    hist8[((size_t)b * SS + s) * TT + lane] = (unsigned char)barg;
}

// ---------------------------------------------------------------------------
// Kernel 4: backtrack via LDS path doubling, 1024 threads, 4-wide batched
// dependent loads. hist8 layout: [b][s][t], rows s=1..511 valid.
// ---------------------------------------------------------------------------
__global__ __launch_bounds__(1024) void backtrack(
    const unsigned char* __restrict__ hist8, const int* __restrict__ bestTag,
    int* __restrict__ out)
{
    __shared__ unsigned char A[511 * 64];
    __shared__ unsigned char Bf[511 * 64];

    const int b   = blockIdx.x;
    const int tid = threadIdx.x;
    const unsigned char* h8 = hist8 + (size_t)b * SS * TT;

    for (int idx = tid; idx < 511 * 64; idx += 1024) A[idx] = h8[idx + 64];
    __syncthreads();

    unsigned char* curT = A;
    unsigned char* nxtT = Bf;
    for (int d = 1; d < 511; d <<= 1) {
        for (int gQ = 0; gQ < 7; gQ++) {
            int i0 = tid + (gQ * 4 + 0) * 1024;
            int i1 = tid + (gQ * 4 + 1) * 1024;
            int i2 = tid + (gQ * 4 + 2) * 1024;
            int i3 = tid + (gQ * 4 + 3) * 1024;
            int s0 = i0 >> 6, s1 = i1 >> 6, s2 = i2 >> 6, s3 = i3 >> 6;
            int a0 = (s0 + d >= 511) ? i0 : (s0 + d) * 64 + (i0 & 63);
            int a1 = (s1 + d >= 511) ? i1 : (s1 + d) * 64 + (i1 & 63);
            int a2 = (s2 + d >= 511) ? i2 : (s2 + d) * 64 + (i2 & 63);
            int a3 = (s3 + d >= 511) ? i3 : (s3 + d) * 64 + (i3 & 63);
            unsigned char q0 = curT[a0], q1 = curT[a1], q2 = curT[a2], q3 = curT[a3];
            int f0 = (s0 + d >= 511) ? i0 : s0 * 64 + q0;
            int f1 = (s1 + d >= 511) ? i1 : s1 * 64 + q1;
            int f2 = (s2 + d >= 511) ? i2 : s2 * 64 + q2;
            int f3 = (s3 + d >= 511) ? i3 : s3 * 64 + q3;
            nxtT[i0] = curT[f0];  nxtT[i1] = curT[f1];
            nxtT[i2] = curT[f2];  nxtT[i3] = curT[f3];
        }
        for (int j = 28; j < 31; j++) {
            int i0 = tid + j * 1024;
            int s0 = i0 >> 6;
            int a0 = (s0 + d >= 511) ? i0 : (s0 + d) * 64 + (i0 & 63);
            unsigned char q0 = curT[a0];
            int f0 = (s0 + d >= 511) ? i0 : s0 * 64 + q0;
            nxtT[i0] = curT[f0];
        }
        {
            int i0 = tid + 31 * 1024;
            if (i0 < 511 * 64) {
                int s0 = i0 >> 6;
                int a0 = (s0 + d >= 511) ? i0 : (s0 + d) * 64 + (i0 & 63);
                unsigned char q0 = curT[a0];
                int f0 = (s0 + d >= 511) ? i0 : s0 * 64 + q0;
                nxtT[i0] = curT[f0];
            }
        }
        __syncthreads();
        unsigned char* tmp = curT; curT = nxtT; nxtT = tmp;
    }

    const int bt = bestTag[b];
    for (int s = tid; s < SS; s += 1024) {
        const int tag = (s == 511) ? bt : (int)curT[s * 64 + bt];
        out[(size_t)b * SS + s] = tag;
    }
}

// ---------------------------------------------------------------------------
extern "C" void kernel_launch(void* const* d_in, const int* in_sizes, int n_in,
                              void* d_out, int out_size, void* d_ws, size_t ws_size,
                              hipStream_t stream)
{
    const float* X     = (const float*)d_in[0];  // [64,512,768]
    const float* W     = (const float*)d_in[1];  // [64,768]
    const float* bias  = (const float*)d_in[2];  // [64]
    const float* trans = (const float*)d_in[3];  // [64,64]
    int* out = (int*)d_out;                      // [64,512] int32

    char* ws = (char*)d_ws;
    float*         em        = (float*)ws;                      // 8,388,608 B
    float*         scoreHist = (float*)(ws + 8388608);          // 8,388,608 B
    unsigned char* hist8     = (unsigned char*)(ws + 16777216); // 2,097,152 B
    int*           bestTag   = (int*)(ws + 18874368);           // 256 B

    emis_gemm<<<dim3(512), dim3(256), 0, stream>>>(X, W, bias, em);
    viterbi_fwd<<<dim3(64), dim3(64), 0, stream>>>(em, trans, scoreHist, bestTag);
    bp_kernel<<<dim3(8176), dim3(256), 0, stream>>>(scoreHist, em, trans, hist8);
    backtrack<<<dim3(64), dim3(1024), 0, stream>>>(hist8, bestTag, out);
}

// Round 9
// 319.077 us; speedup vs baseline: 1.4095x; 1.4095x over previous
//
#include <hip/hip_runtime.h>

#define SS 512
#define DD 768
#define TT 64

// ---------------------------------------------------------------------------
// Kernel 1: emissions GEMM  em[b*512+s][t] = sum_d x[b,s,d]*W[t,d] + bias[t]
// 64x64 tile, grid 512 (2 blocks/CU), 256 threads, thread tile 4x4.
// ---------------------------------------------------------------------------
__global__ __launch_bounds__(256) void emis_gemm(
    const float* __restrict__ X, const float* __restrict__ W,
    const float* __restrict__ bias, float* __restrict__ em)
{
    __shared__ __align__(16) float Xs[16][68];
    __shared__ __align__(16) float Ws[16][68];

    const int tid = threadIdx.x;
    const int m0  = blockIdx.x * 64;
    const int tm  = tid >> 4;
    const int tn  = tid & 15;
    const int lr  = tid >> 2;
    const int lk  = tid & 3;

    float acc[4][4];
#pragma unroll
    for (int i = 0; i < 4; i++)
#pragma unroll
        for (int j = 0; j < 4; j++) acc[i][j] = 0.f;

    float4 xr, wr;
    xr = *(const float4*)&X[(size_t)(m0 + lr) * DD + lk * 4];
    wr = *(const float4*)&W[(size_t)lr * DD + lk * 4];

    for (int t = 0; t < 48; t++) {
        Xs[lk * 4 + 0][lr] = xr.x;  Xs[lk * 4 + 1][lr] = xr.y;
        Xs[lk * 4 + 2][lr] = xr.z;  Xs[lk * 4 + 3][lr] = xr.w;
        Ws[lk * 4 + 0][lr] = wr.x;  Ws[lk * 4 + 1][lr] = wr.y;
        Ws[lk * 4 + 2][lr] = wr.z;  Ws[lk * 4 + 3][lr] = wr.w;
        __syncthreads();

        if (t < 47) {
            const int k0 = (t + 1) * 16;
            xr = *(const float4*)&X[(size_t)(m0 + lr) * DD + k0 + lk * 4];
            wr = *(const float4*)&W[(size_t)lr * DD + k0 + lk * 4];
        }

#pragma unroll
        for (int k = 0; k < 16; k++) {
            float a[4], bv[4];
            *(float4*)&a[0]  = *(const float4*)&Xs[k][tm * 4];
            *(float4*)&bv[0] = *(const float4*)&Ws[k][tn * 4];
#pragma unroll
            for (int i = 0; i < 4; i++)
#pragma unroll
                for (int j = 0; j < 4; j++)
                    acc[i][j] = fmaf(a[i], bv[j], acc[i][j]);
        }
        __syncthreads();
    }

    const float4 bv4 = *(const float4*)&bias[tn * 4];
#pragma unroll
    for (int i = 0; i < 4; i++) {
        const size_t row = (size_t)(m0 + tm * 4 + i);
        float4 o;
        o.x = acc[i][0] + bv4.x;  o.y = acc[i][1] + bv4.y;
        o.z = acc[i][2] + bv4.z;  o.w = acc[i][3] + bv4.w;
        *(float4*)&em[row * TT + tn * 4] = o;
    }
}

// ---------------------------------------------------------------------------
// Kernel 2: Viterbi forward, VALUE ONLY, readlane broadcast + PINNED treg.
// One wave per batch (64 x 64). Zero memory ops on the serial chain:
//   tree -> 64 independent v_readlane (VALU) -> 64 adds -> tree.
// treg[64] (trans column for this lane's cur) is pinned in VGPRs via opaque
// v_mov_b32 asm defs -- the compiler cannot rematerialize them (R5-R7
// showed VGPR=64..84: treg was being re-fetched every step otherwise).
// new_score[cur] = round(max_p round(score[p]+trans[p][cur]) + em[cur])
// == reference bit-exact (monotone rounding; em is lane-constant).
// ---------------------------------------------------------------------------
__global__ __launch_bounds__(64, 1) void viterbi_fwd(
    const float* __restrict__ em, const float* __restrict__ trans,
    float* __restrict__ scoreHist, int* __restrict__ bestTag)
{
    __shared__ __align__(16) float tr_lds[4096];

    const int b    = blockIdx.x;
    const int lane = threadIdx.x;
    const float* emb = em + (size_t)b * SS * TT;
    float* sh = scoreHist + (size_t)b * SS * TT;

    // stage trans into LDS (coalesced), then pin this lane's column in VGPRs
    {
        float4* dst = (float4*)tr_lds;
        const float4* src = (const float4*)trans;
#pragma unroll
        for (int i = 0; i < 16; i++) dst[lane + i * 64] = src[lane + i * 64];
    }
    __syncthreads();

    float treg[TT];
#pragma unroll
    for (int p = 0; p < TT; p++) {
        float tmp = tr_lds[p * TT + lane];
        asm volatile("v_mov_b32 %0, %1" : "=v"(treg[p]) : "v"(tmp));
    }

    float sc = emb[lane];   // score_0[lane]
    sh[lane] = sc;

    float er0 = emb[1 * TT + lane];
    float er1 = emb[2 * TT + lane];
    float er2 = emb[3 * TT + lane];
    float er3 = emb[4 * TT + lane];

    auto step = [&](int s, float em_v) {
        // broadcast score[p] to all lanes via readlane (pure VALU, no mem)
        float v[TT];
#pragma unroll
        for (int p = 0; p < TT; p++) {
            const float sp = __uint_as_float(
                __builtin_amdgcn_readlane(__float_as_uint(sc), p));
            v[p] = sp + treg[p];
        }
        // max3 tree, depth 4, value only
        float t1[22];
#pragma unroll
        for (int i = 0; i < 21; i++)
            t1[i] = fmaxf(fmaxf(v[3 * i], v[3 * i + 1]), v[3 * i + 2]);
        t1[21] = v[63];
        float t2[8];
#pragma unroll
        for (int i = 0; i < 7; i++)
            t2[i] = fmaxf(fmaxf(t1[3 * i], t1[3 * i + 1]), t1[3 * i + 2]);
        t2[7] = t1[21];
        float t3[3];
        t3[0] = fmaxf(fmaxf(t2[0], t2[1]), t2[2]);
        t3[1] = fmaxf(fmaxf(t2[3], t2[4]), t2[5]);
        t3[2] = fmaxf(t2[6], t2[7]);
        sc = fmaxf(fmaxf(t3[0], t3[1]), t3[2]) + em_v;

        sh[s * TT + lane] = sc;   // history for bp_kernel (fire-and-forget)
    };

    for (int sb = 1; sb <= 505; sb += 4) {
        step(sb + 0, er0);  er0 = emb[(sb + 4) * TT + lane];
        step(sb + 1, er1);  er1 = emb[(sb + 5) * TT + lane];
        step(sb + 2, er2);  er2 = emb[(sb + 6) * TT + lane];
        step(sb + 3, er3);  er3 = emb[((sb + 7) <= 511 ? (sb + 7) : 511) * TT + lane];
    }
    step(509, er0);
    step(510, er1);
    step(511, er2);

    // final argmax across lanes (first-index ties)
    float fv = sc;
    int   fa = lane;
#pragma unroll
    for (int m = 1; m <= 32; m <<= 1) {
        const float vo = __shfl_xor(fv, m, 64);
        const int   ao = __shfl_xor(fa, m, 64);
        if (vo > fv || (vo == fv && ao < fa)) { fv = vo; fa = ao; }
    }
    if (lane == 0) bestTag[b] = fa;
}

// ---------------------------------------------------------------------------
// Kernel 3: backpointer recompute, massively parallel. One wave per (b,s),
// lane = cur. v[p] = (score_{s-1}[p] + trans[p][cur]) + em_s[cur] with
// exact reference rounding; left-wins tournament == first-index argmax.
// ---------------------------------------------------------------------------
__global__ __launch_bounds__(256) void bp_kernel(
    const float* __restrict__ scoreHist, const float* __restrict__ em,
    const float* __restrict__ trans, unsigned char* __restrict__ hist8)
{
    __shared__ __align__(16) float tr_lds[4096];  // 16 KB: trans[64][64]
    const int tid = threadIdx.x;
    {
        const float4* src = (const float4*)trans;
        float4* dst = (float4*)tr_lds;
        for (int i = tid; i < 1024; i += 256) dst[i] = src[i];
    }
    __syncthreads();

    const int wv   = tid >> 6;
    const int lane = tid & 63;
    const int g    = blockIdx.x * 4 + wv;   // 0..32703
    const int b    = g / 511;
    const int s    = 1 + (g % 511);

    const float4* sb4 = (const float4*)(scoreHist + ((size_t)b * SS + (s - 1)) * TT);
    const float em_v = em[((size_t)b * SS + s) * TT + lane];

    float treg[TT];
#pragma unroll
    for (int p = 0; p < TT; p++) treg[p] = tr_lds[p * TT + lane];

    float4 sq[16];
#pragma unroll
    for (int i = 0; i < 16; i++) sq[i] = sb4[i];

    float v[TT];
#pragma unroll
    for (int i = 0; i < 16; i++) {
        v[4 * i + 0] = (sq[i].x + treg[4 * i + 0]) + em_v;
        v[4 * i + 1] = (sq[i].y + treg[4 * i + 1]) + em_v;
        v[4 * i + 2] = (sq[i].z + treg[4 * i + 2]) + em_v;
        v[4 * i + 3] = (sq[i].w + treg[4 * i + 3]) + em_v;
    }
    // left-wins tournament (== numpy first-index argmax)
    float m1[32]; int a1[32];
#pragma unroll
    for (int i = 0; i < 32; i++) {
        const bool t = v[2 * i + 1] > v[2 * i];
        m1[i] = t ? v[2 * i + 1] : v[2 * i];
        a1[i] = 2 * i + (t ? 1 : 0);
    }
    float m2[16]; int a2[16];
#pragma unroll
    for (int i = 0; i < 16; i++) {
        const bool t = m1[2 * i + 1] > m1[2 * i];
        m2[i] = t ? m1[2 * i + 1] : m1[2 * i];
        a2[i] = t ? a1[2 * i + 1] : a1[2 * i];
    }
    float m3[8]; int a3[8];
#pragma unroll
    for (int i = 0; i < 8; i++) {
        const bool t = m2[2 * i + 1] > m2[2 * i];
        m3[i] = t ? m2[2 * i + 1] : m2[2 * i];
        a3[i] = t ? a2[2 * i + 1] : a2[2 * i];
    }
    float m4[4]; int a4[4];
#pragma unroll
    for (int i = 0; i < 4; i++) {
        const bool t = m3[2 * i + 1] > m3[2 * i];
        m4[i] = t ? m3[2 * i + 1] : m3[2 * i];
        a4[i] = t ? a3[2 * i + 1] : a3[2 * i];
    }
    float m5[2]; int a5[2];
#pragma unroll
    for (int i = 0; i < 2; i++) {
        const bool t = m4[2 * i + 1] > m4[2 * i];
        m5[i] = t ? m4[2 * i + 1] : m4[2 * i];
        a5[i] = t ? a4[2 * i + 1] : a4[2 * i];
    }
    const bool t6 = m5[1] > m5[0];
    const int barg = t6 ? a5[1] : a5[0];

    hist8[((size_t)b * SS + s) * TT + lane] = (unsigned char)barg;
}

// ---------------------------------------------------------------------------
// Kernel 4: backtrack via LDS path doubling, 1024 threads, 4-wide batched
// dependent loads. hist8 layout: [b][s][t], rows s=1..511 valid.
// ---------------------------------------------------------------------------
__global__ __launch_bounds__(1024) void backtrack(
    const unsigned char* __restrict__ hist8, const int* __restrict__ bestTag,
    int* __restrict__ out)
{
    __shared__ unsigned char A[511 * 64];
    __shared__ unsigned char Bf[511 * 64];

    const int b   = blockIdx.x;
    const int tid = threadIdx.x;
    const unsigned char* h8 = hist8 + (size_t)b * SS * TT;

    for (int idx = tid; idx < 511 * 64; idx += 1024) A[idx] = h8[idx + 64];
    __syncthreads();

    unsigned char* curT = A;
    unsigned char* nxtT = Bf;
    for (int d = 1; d < 511; d <<= 1) {
        for (int gQ = 0; gQ < 7; gQ++) {
            int i0 = tid + (gQ * 4 + 0) * 1024;
            int i1 = tid + (gQ * 4 + 1) * 1024;
            int i2 = tid + (gQ * 4 + 2) * 1024;
            int i3 = tid + (gQ * 4 + 3) * 1024;
            int s0 = i0 >> 6, s1 = i1 >> 6, s2 = i2 >> 6, s3 = i3 >> 6;
            int a0 = (s0 + d >= 511) ? i0 : (s0 + d) * 64 + (i0 & 63);
            int a1 = (s1 + d >= 511) ? i1 : (s1 + d) * 64 + (i1 & 63);
            int a2 = (s2 + d >= 511) ? i2 : (s2 + d) * 64 + (i2 & 63);
            int a3 = (s3 + d >= 511) ? i3 : (s3 + d) * 64 + (i3 & 63);
            unsigned char q0 = curT[a0], q1 = curT[a1], q2 = curT[a2], q3 = curT[a3];
            int f0 = (s0 + d >= 511) ? i0 : s0 * 64 + q0;
            int f1 = (s1 + d >= 511) ? i1 : s1 * 64 + q1;
            int f2 = (s2 + d >= 511) ? i2 : s2 * 64 + q2;
            int f3 = (s3 + d >= 511) ? i3 : s3 * 64 + q3;
            nxtT[i0] = curT[f0];  nxtT[i1] = curT[f1];
            nxtT[i2] = curT[f2];  nxtT[i3] = curT[f3];
        }
        for (int j = 28; j < 31; j++) {
            int i0 = tid + j * 1024;
            int s0 = i0 >> 6;
            int a0 = (s0 + d >= 511) ? i0 : (s0 + d) * 64 + (i0 & 63);
            unsigned char q0 = curT[a0];
            int f0 = (s0 + d >= 511) ? i0 : s0 * 64 + q0;
            nxtT[i0] = curT[f0];
        }
        {
            int i0 = tid + 31 * 1024;
            if (i0 < 511 * 64) {
                int s0 = i0 >> 6;
                int a0 = (s0 + d >= 511) ? i0 : (s0 + d) * 64 + (i0 & 63);
                unsigned char q0 = curT[a0];
                int f0 = (s0 + d >= 511) ? i0 : s0 * 64 + q0;
                nxtT[i0] = curT[f0];
            }
        }
        __syncthreads();
        unsigned char* tmp = curT; curT = nxtT; nxtT = tmp;
    }

    const int bt = bestTag[b];
    for (int s = tid; s < SS; s += 1024) {
        const int tag = (s == 511) ? bt : (int)curT[s * 64 + bt];
        out[(size_t)b * SS + s] = tag;
    }
}

// ---------------------------------------------------------------------------
extern "C" void kernel_launch(void* const* d_in, const int* in_sizes, int n_in,
                              void* d_out, int out_size, void* d_ws, size_t ws_size,
                              hipStream_t stream)
{
    const float* X     = (const float*)d_in[0];  // [64,512,768]
    const float* W     = (const float*)d_in[1];  // [64,768]
    const float* bias  = (const float*)d_in[2];  // [64]
    const float* trans = (const float*)d_in[3];  // [64,64]
    int* out = (int*)d_out;                      // [64,512] int32

    char* ws = (char*)d_ws;
    float*         em        = (float*)ws;                      // 8,388,608 B
    float*         scoreHist = (float*)(ws + 8388608);          // 8,388,608 B
    unsigned char* hist8     = (unsigned char*)(ws + 16777216); // 2,097,152 B
    int*           bestTag   = (int*)(ws + 18874368);           // 256 B

    emis_gemm<<<dim3(512), dim3(256), 0, stream>>>(X, W, bias, em);
    viterbi_fwd<<<dim3(64), dim3(64), 0, stream>>>(em, trans, scoreHist, bestTag);
    bp_kernel<<<dim3(8176), dim3(256), 0, stream>>>(scoreHist, em, trans, hist8);
    backtrack<<<dim3(64), dim3(1024), 0, stream>>>(hist8, bestTag, out);
}

// Round 10
// 267.851 us; speedup vs baseline: 1.6790x; 1.1912x over previous
//
#include <hip/hip_runtime.h>

#define SS 512
#define DD 768
#define TT 64

typedef __attribute__((ext_vector_type(2))) float f32x2;

__device__ __forceinline__ f32x2 vmax2(f32x2 a, f32x2 b) {
    return __builtin_elementwise_max(a, b);
}

// ---------------------------------------------------------------------------
// Kernel 1: emissions GEMM  em[b*512+s][t] = sum_d x[b,s,d]*W[t,d] + bias[t]
// 64x64 tile, grid 512 (2 blocks/CU), 256 threads, thread tile 4x4.
// ---------------------------------------------------------------------------
__global__ __launch_bounds__(256) void emis_gemm(
    const float* __restrict__ X, const float* __restrict__ W,
    const float* __restrict__ bias, float* __restrict__ em)
{
    __shared__ __align__(16) float Xs[16][68];
    __shared__ __align__(16) float Ws[16][68];

    const int tid = threadIdx.x;
    const int m0  = blockIdx.x * 64;
    const int tm  = tid >> 4;
    const int tn  = tid & 15;
    const int lr  = tid >> 2;
    const int lk  = tid & 3;

    float acc[4][4];
#pragma unroll
    for (int i = 0; i < 4; i++)
#pragma unroll
        for (int j = 0; j < 4; j++) acc[i][j] = 0.f;

    float4 xr, wr;
    xr = *(const float4*)&X[(size_t)(m0 + lr) * DD + lk * 4];
    wr = *(const float4*)&W[(size_t)lr * DD + lk * 4];

    for (int t = 0; t < 48; t++) {
        Xs[lk * 4 + 0][lr] = xr.x;  Xs[lk * 4 + 1][lr] = xr.y;
        Xs[lk * 4 + 2][lr] = xr.z;  Xs[lk * 4 + 3][lr] = xr.w;
        Ws[lk * 4 + 0][lr] = wr.x;  Ws[lk * 4 + 1][lr] = wr.y;
        Ws[lk * 4 + 2][lr] = wr.z;  Ws[lk * 4 + 3][lr] = wr.w;
        __syncthreads();

        if (t < 47) {
            const int k0 = (t + 1) * 16;
            xr = *(const float4*)&X[(size_t)(m0 + lr) * DD + k0 + lk * 4];
            wr = *(const float4*)&W[(size_t)lr * DD + k0 + lk * 4];
        }

#pragma unroll
        for (int k = 0; k < 16; k++) {
            float a[4], bv[4];
            *(float4*)&a[0]  = *(const float4*)&Xs[k][tm * 4];
            *(float4*)&bv[0] = *(const float4*)&Ws[k][tn * 4];
#pragma unroll
            for (int i = 0; i < 4; i++)
#pragma unroll
                for (int j = 0; j < 4; j++)
                    acc[i][j] = fmaf(a[i], bv[j], acc[i][j]);
        }
        __syncthreads();
    }

    const float4 bv4 = *(const float4*)&bias[tn * 4];
#pragma unroll
    for (int i = 0; i < 4; i++) {
        const size_t row = (size_t)(m0 + tm * 4 + i);
        float4 o;
        o.x = acc[i][0] + bv4.x;  o.y = acc[i][1] + bv4.y;
        o.z = acc[i][2] + bv4.z;  o.w = acc[i][3] + bv4.w;
        *(float4*)&em[row * TT + tn * 4] = o;
    }
}

// ---------------------------------------------------------------------------
// Kernel 2: Viterbi forward, VALUE ONLY. One wave per batch (64 x 64).
// amdgpu_waves_per_eu(1,1): occupancy target 1 wave/EU -> full 512-VGPR
// budget so tpk[32] (packed trans column) stays register-resident
// (R5-R9 all showed VGPR<=84: the allocator's default pressure target
// spilled/refetched the 64 trans values every step).
// Step: 16 broadcast ds_read_b128 (scores) -> 32 v_pk_add_f32 ->
// 31 v_pk_max_f32 tree -> fmax -> +em -> ds_write. Bit-exact vs reference:
// candidates rounded once as (score+trans), maxes exact, +em rounds once
// (monotone rounding commutes with max; em is lane-constant).
// ---------------------------------------------------------------------------
__global__ __launch_bounds__(64)
__attribute__((amdgpu_waves_per_eu(1, 1)))
void viterbi_fwd(
    const float* __restrict__ em, const float* __restrict__ trans,
    float* __restrict__ scoreHist, int* __restrict__ bestTag)
{
    __shared__ __align__(16) float sc_lds[TT];
    __shared__ __align__(16) float tr_lds[4096];

    const int b    = blockIdx.x;
    const int lane = threadIdx.x;
    const float* emb = em + (size_t)b * SS * TT;
    float* sh = scoreHist + (size_t)b * SS * TT;

    // stage trans into LDS (coalesced), then load this lane's column packed
    {
        float4* dst = (float4*)tr_lds;
        const float4* src = (const float4*)trans;
#pragma unroll
        for (int i = 0; i < 16; i++) dst[lane + i * 64] = src[lane + i * 64];
    }
    __syncthreads();

    // tpk[j] = (trans[2j][lane], trans[2j+1][lane])
    f32x2 tpk[32];
#pragma unroll
    for (int j = 0; j < 32; j++) {
        tpk[j].x = tr_lds[(2 * j) * TT + lane];
        tpk[j].y = tr_lds[(2 * j + 1) * TT + lane];
    }

    const float em0 = emb[lane];
    sc_lds[lane] = em0;
    sh[lane] = em0;   // score_0
    float sc = em0;

    float er0 = emb[1 * TT + lane];
    float er1 = emb[2 * TT + lane];
    float er2 = emb[3 * TT + lane];
    float er3 = emb[4 * TT + lane];

    // prime score reads for step 1 (DS FIFO: ordered after the init write)
    float4 sq[16];
    {
        const float4* sb = (const float4*)sc_lds;
#pragma unroll
        for (int i = 0; i < 16; i++) sq[i] = sb[i];
    }

    auto step = [&](int s, float em_v) {
        // packed candidates: pk[j] = (s2j + t2j, s2j1 + t2j1)
        const f32x2* sq2 = (const f32x2*)sq;
        f32x2 pk[32];
#pragma unroll
        for (int j = 0; j < 32; j++) pk[j] = sq2[j] + tpk[j];

        // packed max tree: 16+8+4+2+1 = 31 pk_max
#pragma unroll
        for (int m = 16; m >= 1; m >>= 1)
#pragma unroll
            for (int j = 0; j < 16; j++) {
                if (j < m) pk[j] = vmax2(pk[j], pk[j + m]);
            }
        sc = fmaxf(pk[0].x, pk[0].y) + em_v;

        sc_lds[lane] = sc;                  // end of serial chain
        {                                   // issue next step's reads NOW
            const float4* sb = (const float4*)sc_lds;
#pragma unroll
            for (int i = 0; i < 16; i++) sq[i] = sb[i];
        }
        sh[s * TT + lane] = sc;             // history for bp_kernel
    };

    for (int sb = 1; sb <= 505; sb += 4) {
        step(sb + 0, er0);  er0 = emb[(sb + 4) * TT + lane];
        step(sb + 1, er1);  er1 = emb[(sb + 5) * TT + lane];
        step(sb + 2, er2);  er2 = emb[(sb + 6) * TT + lane];
        step(sb + 3, er3);  er3 = emb[((sb + 7) <= 511 ? (sb + 7) : 511) * TT + lane];
    }
    step(509, er0);
    step(510, er1);
    step(511, er2);

    // final argmax across lanes (first-index ties)
    float fv = sc;
    int   fa = lane;
#pragma unroll
    for (int m = 1; m <= 32; m <<= 1) {
        const float vo = __shfl_xor(fv, m, 64);
        const int   ao = __shfl_xor(fa, m, 64);
        if (vo > fv || (vo == fv && ao < fa)) { fv = vo; fa = ao; }
    }
    if (lane == 0) bestTag[b] = fa;
}

// ---------------------------------------------------------------------------
// Kernel 3: backpointer recompute, massively parallel. One wave per (b,s),
// lane = cur. v[p] = (score_{s-1}[p] + trans[p][cur]) + em_s[cur] with
// exact reference rounding; left-wins tournament == first-index argmax.
// ---------------------------------------------------------------------------
__global__ __launch_bounds__(256) void bp_kernel(
    const float* __restrict__ scoreHist, const float* __restrict__ em,
    const float* __restrict__ trans, unsigned char* __restrict__ hist8)
{
    __shared__ __align__(16) float tr_lds[4096];  // 16 KB: trans[64][64]
    const int tid = threadIdx.x;
    {
        const float4* src = (const float4*)trans;
        float4* dst = (float4*)tr_lds;
        for (int i = tid; i < 1024; i += 256) dst[i] = src[i];
    }
    __syncthreads();

    const int wv   = tid >> 6;
    const int lane = tid & 63;
    const int g    = blockIdx.x * 4 + wv;   // 0..32703
    const int b    = g / 511;
    const int s    = 1 + (g % 511);

    const float4* sb4 = (const float4*)(scoreHist + ((size_t)b * SS + (s - 1)) * TT);
    const float em_v = em[((size_t)b * SS + s) * TT + lane];

    float treg[TT];
#pragma unroll
    for (int p = 0; p < TT; p++) treg[p] = tr_lds[p * TT + lane];

    float4 sq[16];
#pragma unroll
    for (int i = 0; i < 16; i++) sq[i] = sb4[i];

    float v[TT];
#pragma unroll
    for (int i = 0; i < 16; i++) {
        v[4 * i + 0] = (sq[i].x + treg[4 * i + 0]) + em_v;
        v[4 * i + 1] = (sq[i].y + treg[4 * i + 1]) + em_v;
        v[4 * i + 2] = (sq[i].z + treg[4 * i + 2]) + em_v;
        v[4 * i + 3] = (sq[i].w + treg[4 * i + 3]) + em_v;
    }
    // left-wins tournament (== numpy first-index argmax)
    float m1[32]; int a1[32];
#pragma unroll
    for (int i = 0; i < 32; i++) {
        const bool t = v[2 * i + 1] > v[2 * i];
        m1[i] = t ? v[2 * i + 1] : v[2 * i];
        a1[i] = 2 * i + (t ? 1 : 0);
    }
    float m2[16]; int a2[16];
#pragma unroll
    for (int i = 0; i < 16; i++) {
        const bool t = m1[2 * i + 1] > m1[2 * i];
        m2[i] = t ? m1[2 * i + 1] : m1[2 * i];
        a2[i] = t ? a1[2 * i + 1] : a1[2 * i];
    }
    float m3[8]; int a3[8];
#pragma unroll
    for (int i = 0; i < 8; i++) {
        const bool t = m2[2 * i + 1] > m2[2 * i];
        m3[i] = t ? m2[2 * i + 1] : m2[2 * i];
        a3[i] = t ? a2[2 * i + 1] : a2[2 * i];
    }
    float m4[4]; int a4[4];
#pragma unroll
    for (int i = 0; i < 4; i++) {
        const bool t = m3[2 * i + 1] > m3[2 * i];
        m4[i] = t ? m3[2 * i + 1] : m3[2 * i];
        a4[i] = t ? a3[2 * i + 1] : a3[2 * i];
    }
    float m5[2]; int a5[2];
#pragma unroll
    for (int i = 0; i < 2; i++) {
        const bool t = m4[2 * i + 1] > m4[2 * i];
        m5[i] = t ? m4[2 * i + 1] : m4[2 * i];
        a5[i] = t ? a4[2 * i + 1] : a4[2 * i];
    }
    const bool t6 = m5[1] > m5[0];
    const int barg = t6 ? a5[1] : a5[0];

    hist8[((size_t)b * SS + s) * TT + lane] = (unsigned char)barg;
}

// ---------------------------------------------------------------------------
// Kernel 4: backtrack via LDS path doubling, 1024 threads, 4-wide batched
// dependent loads. hist8 layout: [b][s][t], rows s=1..511 valid.
// ---------------------------------------------------------------------------
__global__ __launch_bounds__(1024) void backtrack(
    const unsigned char* __restrict__ hist8, const int* __restrict__ bestTag,
    int* __restrict__ out)
{
    __shared__ unsigned char A[511 * 64];
    __shared__ unsigned char Bf[511 * 64];

    const int b   = blockIdx.x;
    const int tid = threadIdx.x;
    const unsigned char* h8 = hist8 + (size_t)b * SS * TT;

    for (int idx = tid; idx < 511 * 64; idx += 1024) A[idx] = h8[idx + 64];
    __syncthreads();

    unsigned char* curT = A;
    unsigned char* nxtT = Bf;
    for (int d = 1; d < 511; d <<= 1) {
        for (int gQ = 0; gQ < 7; gQ++) {
            int i0 = tid + (gQ * 4 + 0) * 1024;
            int i1 = tid + (gQ * 4 + 1) * 1024;
            int i2 = tid + (gQ * 4 + 2) * 1024;
            int i3 = tid + (gQ * 4 + 3) * 1024;
            int s0 = i0 >> 6, s1 = i1 >> 6, s2 = i2 >> 6, s3 = i3 >> 6;
            int a0 = (s0 + d >= 511) ? i0 : (s0 + d) * 64 + (i0 & 63);
            int a1 = (s1 + d >= 511) ? i1 : (s1 + d) * 64 + (i1 & 63);
            int a2 = (s2 + d >= 511) ? i2 : (s2 + d) * 64 + (i2 & 63);
            int a3 = (s3 + d >= 511) ? i3 : (s3 + d) * 64 + (i3 & 63);
            unsigned char q0 = curT[a0], q1 = curT[a1], q2 = curT[a2], q3 = curT[a3];
            int f0 = (s0 + d >= 511) ? i0 : s0 * 64 + q0;
            int f1 = (s1 + d >= 511) ? i1 : s1 * 64 + q1;
            int f2 = (s2 + d >= 511) ? i2 : s2 * 64 + q2;
            int f3 = (s3 + d >= 511) ? i3 : s3 * 64 + q3;
            nxtT[i0] = curT[f0];  nxtT[i1] = curT[f1];
            nxtT[i2] = curT[f2];  nxtT[i3] = curT[f3];
        }
        for (int j = 28; j < 31; j++) {
            int i0 = tid + j * 1024;
            int s0 = i0 >> 6;
            int a0 = (s0 + d >= 511) ? i0 : (s0 + d) * 64 + (i0 & 63);
            unsigned char q0 = curT[a0];
            int f0 = (s0 + d >= 511) ? i0 : s0 * 64 + q0;
            nxtT[i0] = curT[f0];
        }
        {
            int i0 = tid + 31 * 1024;
            if (i0 < 511 * 64) {
                int s0 = i0 >> 6;
                int a0 = (s0 + d >= 511) ? i0 : (s0 + d) * 64 + (i0 & 63);
                unsigned char q0 = curT[a0];
                int f0 = (s0 + d >= 511) ? i0 : s0 * 64 + q0;
                nxtT[i0] = curT[f0];
            }
        }
        __syncthreads();
        unsigned char* tmp = curT; curT = nxtT; nxtT = tmp;
    }

    const int bt = bestTag[b];
    for (int s = tid; s < SS; s += 1024) {
        const int tag = (s == 511) ? bt : (int)curT[s * 64 + bt];
        out[(size_t)b * SS + s] = tag;
    }
}

// ---------------------------------------------------------------------------
extern "C" void kernel_launch(void* const* d_in, const int* in_sizes, int n_in,
                              void* d_out, int out_size, void* d_ws, size_t ws_size,
                              hipStream_t stream)
{
    const float* X     = (const float*)d_in[0];  // [64,512,768]
    const float* W     = (const float*)d_in[1];  // [64,768]
    const float* bias  = (const float*)d_in[2];  // [64]
    const float* trans = (const float*)d_in[3];  // [64,64]
    int* out = (int*)d_out;                      // [64,512] int32

    char* ws = (char*)d_ws;
    float*         em        = (float*)ws;                      // 8,388,608 B
    float*         scoreHist = (float*)(ws + 8388608);          // 8,388,608 B
    unsigned char* hist8     = (unsigned char*)(ws + 16777216); // 2,097,152 B
    int*           bestTag   = (int*)(ws + 18874368);           // 256 B

    emis_gemm<<<dim3(512), dim3(256), 0, stream>>>(X, W, bias, em);
    viterbi_fwd<<<dim3(64), dim3(64), 0, stream>>>(em, trans, scoreHist, bestTag);
    bp_kernel<<<dim3(8176), dim3(256), 0, stream>>>(scoreHist, em, trans, hist8);
    backtrack<<<dim3(64), dim3(1024), 0, stream>>>(hist8, bestTag, out);
}